// Round 10
// baseline (421.861 us; speedup 1.0000x reference)
//
#include <hip/hip_runtime.h>
#include <hip/hip_bf16.h>
#include <stdint.h>

typedef __hip_bfloat16 bf16;
typedef __attribute__((ext_vector_type(8))) short bf16x8;  // 8 bf16 in 4 VGPRs
typedef __attribute__((ext_vector_type(4))) float f32x4;

__device__ inline float bf2f(bf16 v) { return __bfloat162float(v); }
__device__ inline bf16 f2bf(float f) { return __float2bfloat16(f); }

__device__ inline void glds16(const void* g, void* l) {
    __builtin_amdgcn_global_load_lds(
        (const __attribute__((address_space(1))) uint32_t*)g,
        (__attribute__((address_space(3))) uint32_t*)l, 16, 0, 0);
}

// ---------------- conv_x: fp32 [n] -> bf16 [n], same layout ----------------
__global__ __launch_bounds__(256) void conv_x(const float* __restrict__ in,
                                              bf16* __restrict__ out)
{
    size_t i = ((size_t)blockIdx.x * 256 + threadIdx.x) * 8;
    float4 f0 = *(const float4*)(in + i);
    float4 f1 = *(const float4*)(in + i + 4);
    union { bf16x8 v; bf16 e[8]; } u;
    u.e[0] = f2bf(f0.x); u.e[1] = f2bf(f0.y); u.e[2] = f2bf(f0.z); u.e[3] = f2bf(f0.w);
    u.e[4] = f2bf(f1.x); u.e[5] = f2bf(f1.y); u.e[6] = f2bf(f1.z); u.e[7] = f2bf(f1.w);
    *(bf16x8*)(out + i) = u.v;
}

// ---- conv_wt: fp32 W[K][N] -> bf16 Wt[N][K] (64x64 LDS-tiled transpose) ----
__global__ __launch_bounds__(256) void conv_wt(const float* __restrict__ W,
                                               bf16* __restrict__ Wt, int N, int K)
{
    __shared__ bf16 t[64][72];
    const int n0 = blockIdx.x * 64, k0 = blockIdx.y * 64;
    const int tid = threadIdx.x;
#pragma unroll
    for (int p = 0; p < 4; ++p) {
        int idx = p * 256 + tid;
        int kr = idx >> 4, c4 = idx & 15;
        float4 f = *(const float4*)(W + (size_t)(k0 + kr) * N + n0 + c4 * 4);
        t[kr][c4 * 4 + 0] = f2bf(f.x); t[kr][c4 * 4 + 1] = f2bf(f.y);
        t[kr][c4 * 4 + 2] = f2bf(f.z); t[kr][c4 * 4 + 3] = f2bf(f.w);
    }
    __syncthreads();
#pragma unroll
    for (int p = 0; p < 2; ++p) {
        int idx = p * 256 + tid;
        int nr = idx >> 3, ch = idx & 7;
        union { bf16x8 v; bf16 e[8]; } u;
#pragma unroll
        for (int j = 0; j < 8; ++j) u.e[j] = t[ch * 8 + j][nr];
        *(bf16x8*)(Wt + (size_t)(n0 + nr) * K + k0 + ch * 8) = u.v;
    }
}

// -------- m97-structure GEMM: out[M,N] = A(bf16)[M,K] @ Bt(bf16)[N,K]^T + bias --------
// 128x128 tile, BK=32, 256 thr (4 waves, 2x2), global_load_lds width-16 staging.
template <bool OUTF32>
__global__ __launch_bounds__(256) void gemm_bt(
    const bf16* __restrict__ A, const bf16* __restrict__ Bt,
    const float* __restrict__ bias, int M, int N, int K, void* __restrict__ outv)
{
    __shared__ __align__(16) bf16 sa[128 * 32];
    __shared__ __align__(16) bf16 sb[128 * 32];

    const int tid  = threadIdx.x;
    const int wave = tid >> 6, lane = tid & 63;
    const int quad = lane >> 4, l16 = lane & 15;
    const int wm = wave >> 1, wn = wave & 1;
    const int row0 = blockIdx.x * 128, n0 = blockIdx.y * 128;

    f32x4 acc[4][4] = {};

    const int sm = wave * 16 + (lane >> 2);   // staged row (0..63) per half
    const int sk = (lane & 3) * 8;
    const bf16* ga = A  + (size_t)(row0 + sm) * K + sk;
    const bf16* gb = Bt + (size_t)(n0  + sm) * K + sk;
    bf16* la = sa + wave * 512;               // lane*16B appended by HW
    bf16* lb = sb + wave * 512;

    for (int k0 = 0; k0 < K; k0 += 32) {
        __syncthreads();
        glds16(ga + k0, la);
        glds16(ga + k0 + (size_t)64 * K, la + 2048);
        glds16(gb + k0, lb);
        glds16(gb + k0 + (size_t)64 * K, lb + 2048);
        __syncthreads();

        bf16x8 af[4], bfr[4];
#pragma unroll
        for (int mi = 0; mi < 4; ++mi)
            af[mi] = *(const bf16x8*)&sa[(wm * 64 + mi * 16 + l16) * 32 + quad * 8];
#pragma unroll
        for (int ni = 0; ni < 4; ++ni)
            bfr[ni] = *(const bf16x8*)&sb[(wn * 64 + ni * 16 + l16) * 32 + quad * 8];
#pragma unroll
        for (int mi = 0; mi < 4; ++mi)
#pragma unroll
            for (int ni = 0; ni < 4; ++ni)
                acc[mi][ni] = __builtin_amdgcn_mfma_f32_16x16x32_bf16(
                    af[mi], bfr[ni], acc[mi][ni], 0, 0, 0);
    }

#pragma unroll
    for (int ni = 0; ni < 4; ++ni) {
        int col = n0 + wn * 64 + ni * 16 + l16;
        float bvv = bias[col];
#pragma unroll
        for (int mi = 0; mi < 4; ++mi) {
#pragma unroll
            for (int r = 0; r < 4; ++r) {
                int row = row0 + wm * 64 + mi * 16 + quad * 4 + r;
                float v = acc[mi][ni][r] + bvv;
                if (OUTF32) ((float*)outv)[(size_t)row * N + col] = v;
                else        ((bf16*)outv)[(size_t)row * N + col] = f2bf(v);
            }
        }
    }
}

// ---- rope_k: qkv[4096][3072] bf16 -> q,k [bh][t][64] bf16 (q scaled 0.125) ----
__global__ __launch_bounds__(256) void rope_k(
    const bf16* __restrict__ qkv, bf16* __restrict__ q, bf16* __restrict__ k)
{
    int gid = blockIdx.x * 256 + threadIdx.x;   // [0, 2^21)
    int p  = gid & 31, d0 = p * 2;
    int t  = (gid >> 5) & 2047;
    int h  = (gid >> 16) & 15;
    int b  = gid >> 20;

    size_t src = ((size_t)(b * 2048 + t)) * 3072 + h * 64 + d0;
    size_t dst = (((size_t)(b * 16 + h)) * 2048 + t) * 64 + d0;

    float invf = expf(-(float)d0 * (9.210340371976184f / 64.0f));
    float sn, cs;
    sincosf((float)t * invf, &sn, &cs);

    float q0 = bf2f(qkv[src]),        q1 = bf2f(qkv[src + 1]);
    float k0 = bf2f(qkv[src + 1024]), k1 = bf2f(qkv[src + 1025]);
    q[dst]     = f2bf((q0 * cs - q1 * sn) * 0.125f);
    q[dst + 1] = f2bf((q1 * cs + q0 * sn) * 0.125f);
    k[dst]     = f2bf(k0 * cs - k1 * sn);
    k[dst + 1] = f2bf(k1 * cs + k0 * sn);
}

// ---- transpose_v: qkv v-part -> vt [bh][64 d][2048 t] (64x64 LDS tiles) ----
__global__ __launch_bounds__(256) void transpose_v(
    const bf16* __restrict__ qkv, bf16* __restrict__ vt)
{
    __shared__ bf16 t[64][72];
    const int t0 = blockIdx.x * 64;
    const int bh = blockIdx.y, b = bh >> 4, h = bh & 15;
    const int tid = threadIdx.x;
#pragma unroll
    for (int p = 0; p < 2; ++p) {
        int idx = p * 256 + tid;
        int tr = idx >> 3, ch = idx & 7;
        bf16x8 v = *(const bf16x8*)(qkv + ((size_t)(b * 2048 + t0 + tr)) * 3072
                                    + 2048 + h * 64 + ch * 8);
#pragma unroll
        for (int j = 0; j < 8; ++j) t[tr][ch * 8 + j] = ((const bf16*)&v)[j];
    }
    __syncthreads();
#pragma unroll
    for (int p = 0; p < 2; ++p) {
        int idx = p * 256 + tid;
        int dr = idx >> 3, ch = idx & 7;
        union { bf16x8 v; bf16 e[8]; } u;
#pragma unroll
        for (int j = 0; j < 8; ++j) u.e[j] = t[ch * 8 + j][dr];
        *(bf16x8*)(vt + ((size_t)bh * 64 + dr) * 2048 + t0 + ch * 8) = u.v;
    }
}

// ---- Flash attention, causal, barrier-free. ----
// q,k: [bh][2048][64] bf16 (q pre-scaled). vt: [bh][64][2048] bf16.
// y: [B,T,H*D] bf16. 256 thr = 4 waves; wave owns 16 q-rows; 128 keys/iter.
__global__ __launch_bounds__(256) void attn_k(
    const bf16* __restrict__ qg, const bf16* __restrict__ kg,
    const bf16* __restrict__ vtg, bf16* __restrict__ y)
{
    // per-wave P slice: 16 rows x 128 cols (+8 pad). XOR-chunk swizzle
    // (chunk ^ row_quad) -> scalar writes 2-way same-dword (free),
    // b128 reads 2-way (free per m136). [R9 bug: was [72] -> OOB aliasing]
    __shared__ __align__(16) bf16 pL[4][16][136];

    const int tid  = threadIdx.x;
    const int wave = tid >> 6, lane = tid & 63;
    const int quad = lane >> 4, l16 = lane & 15;
    const int qb = blockIdx.x * 64;
    const int bh = blockIdx.y;
    const bf16* Q  = qg  + (size_t)bh * 2048 * 64;
    const bf16* K  = kg  + (size_t)bh * 2048 * 64;
    const bf16* Vt = vtg + (size_t)bh * 64 * 2048;
    const int q0 = qb + wave * 16;

    bf16x8 aq[2];
    aq[0] = *(const bf16x8*)(Q + (size_t)(q0 + l16) * 64 + quad * 8);
    aq[1] = *(const bf16x8*)(Q + (size_t)(q0 + l16) * 64 + 32 + quad * 8);

    f32x4 o[4] = {};
    float m_r[4] = {-1e30f, -1e30f, -1e30f, -1e30f};
    float l_r[4] = {0.f, 0.f, 0.f, 0.f};

    for (int kt = 0; kt <= q0 + 15; kt += 128) {
        const int nlast = min(7, (q0 - kt) >> 4);   // kt <= q0 guaranteed
        f32x4 sc[8];
        // ---- S = Q K^T over present 16-key subtiles ----
#pragma unroll
        for (int nt = 0; nt < 8; ++nt) {
            if (nt > nlast) continue;
            f32x4 s0 = {};
            bf16x8 bk0 = *(const bf16x8*)(K + (size_t)(kt + nt * 16 + l16) * 64 + quad * 8);
            s0 = __builtin_amdgcn_mfma_f32_16x16x32_bf16(aq[0], bk0, s0, 0, 0, 0);
            bf16x8 bk1 = *(const bf16x8*)(K + (size_t)(kt + nt * 16 + l16) * 64 + 32 + quad * 8);
            sc[nt] = __builtin_amdgcn_mfma_f32_16x16x32_bf16(aq[1], bk1, s0, 0, 0, 0);
        }
        // ---- causal mask: only the diagonal subtile ----
        {
            const int diag = (q0 - kt) >> 4;
            if (diag <= 7) {
                int key = kt + diag * 16 + l16;
#pragma unroll
                for (int r = 0; r < 4; ++r) {
                    int row = q0 + quad * 4 + r;
                    if (key > row) sc[diag][r] = -1e30f;
                }
            }
        }
        // ---- online softmax ----
        float rowmax[4] = {-1e30f, -1e30f, -1e30f, -1e30f};
#pragma unroll
        for (int nt = 0; nt < 8; ++nt) {
            if (nt > nlast) continue;
#pragma unroll
            for (int r = 0; r < 4; ++r) rowmax[r] = fmaxf(rowmax[r], sc[nt][r]);
        }
#pragma unroll
        for (int off = 1; off < 16; off <<= 1)
#pragma unroll
            for (int r = 0; r < 4; ++r)
                rowmax[r] = fmaxf(rowmax[r], __shfl_xor(rowmax[r], off));

        float alpha[4];
#pragma unroll
        for (int r = 0; r < 4; ++r) {
            float mn = fmaxf(m_r[r], rowmax[r]);
            alpha[r] = __expf(m_r[r] - mn);
            m_r[r] = mn;
        }
        float rs[4] = {0.f, 0.f, 0.f, 0.f};
#pragma unroll
        for (int nt = 0; nt < 8; ++nt) {
            if (nt > nlast) continue;
#pragma unroll
            for (int r = 0; r < 4; ++r) {
                float p = __expf(sc[nt][r] - m_r[r]);
                sc[nt][r] = p;
                rs[r] += p;
            }
        }
#pragma unroll
        for (int off = 1; off < 16; off <<= 1)
#pragma unroll
            for (int r = 0; r < 4; ++r) rs[r] += __shfl_xor(rs[r], off);
#pragma unroll
        for (int r = 0; r < 4; ++r) l_r[r] = l_r[r] * alpha[r] + rs[r];
#pragma unroll
        for (int nt = 0; nt < 4; ++nt)
#pragma unroll
            for (int r = 0; r < 4; ++r) o[nt][r] *= alpha[r];

        // ---- P -> per-wave LDS (swizzled), no barrier needed ----
#pragma unroll
        for (int nt = 0; nt < 8; ++nt) {
            if (nt > nlast) continue;
            int blk = (2 * nt + (l16 >> 3)) ^ quad;
#pragma unroll
            for (int r = 0; r < 4; ++r)
                pL[wave][quad * 4 + r][blk * 8 + (l16 & 7)] = f2bf(sc[nt][r]);
        }
        if (nlast < 7 && !(nlast & 1)) {            // zero garbage half-chunk
            int blk = (2 * (nlast + 1) + (l16 >> 3)) ^ quad;
#pragma unroll
            for (int r = 0; r < 4; ++r)
                pL[wave][quad * 4 + r][blk * 8 + (l16 & 7)] = f2bf(0.f);
        }
        // ---- O += P V over present 32-key chunks ----
#pragma unroll
        for (int c = 0; c < 4; ++c) {
            if (c > (nlast >> 1)) continue;
            bf16x8 pa = *(const bf16x8*)&pL[wave][l16][(((4 * c + quad) ^ (l16 >> 2)) * 8)];
#pragma unroll
            for (int dnt = 0; dnt < 4; ++dnt) {
                bf16x8 vb = *(const bf16x8*)(Vt + (size_t)(dnt * 16 + l16) * 2048
                                             + kt + c * 32 + quad * 8);
                o[dnt] = __builtin_amdgcn_mfma_f32_16x16x32_bf16(pa, vb, o[dnt], 0, 0, 0);
            }
        }
    }

    const int b = bh >> 4, h = bh & 15;
#pragma unroll
    for (int r = 0; r < 4; ++r) {
        float inv = 1.0f / l_r[r];
        int qq = q0 + quad * 4 + r;
#pragma unroll
        for (int nt = 0; nt < 4; ++nt) {
            int d = nt * 16 + l16;
            y[((size_t)(b * 2048 + qq)) * 1024 + h * 64 + d] = f2bf(o[nt][r] * inv);
        }
    }
}

extern "C" void kernel_launch(void* const* d_in, const int* in_sizes, int n_in,
                              void* d_out, int out_size, void* d_ws, size_t ws_size,
                              hipStream_t stream) {
    const float* x      = (const float*)d_in[0];
    const float* w_attn = (const float*)d_in[1];
    const float* b_attn = (const float*)d_in[2];
    const float* w_proj = (const float*)d_in[3];
    const float* b_proj = (const float*)d_in[4];
    float* out = (float*)d_out;                      // fp32 output

    // ws (bf16 elems): xbf | wat | wpt | qkv | q | k | vt | y  = 75.5 MB
    bf16* xbf = (bf16*)d_ws;                         // [4096][1024]
    bf16* wat = xbf + (size_t)4194304;               // [3072][1024] (B^T)
    bf16* wpt = wat + (size_t)3145728;               // [1024][1024] (B^T)
    bf16* qkv = wpt + (size_t)1048576;               // [4096][3072]
    bf16* qh  = qkv + (size_t)12582912;              // [bh][2048][64]
    bf16* kh  = qh  + (size_t)4194304;
    bf16* vt  = kh  + (size_t)4194304;               // [bh][64][2048]
    bf16* yws = vt  + (size_t)4194304;               // [4096][1024]

    dim3 blk(256);
    conv_x<<<dim3(2048), blk, 0, stream>>>(x, xbf);
    conv_wt<<<dim3(48, 16), blk, 0, stream>>>(w_attn, wat, 3072, 1024);
    conv_wt<<<dim3(16, 16), blk, 0, stream>>>(w_proj, wpt, 1024, 1024);
    // 1) qkv = x @ w_attn + b_attn
    gemm_bt<false><<<dim3(32, 24), blk, 0, stream>>>(xbf, wat, b_attn,
                                                     4096, 3072, 1024, qkv);
    // 2) RoPE (q,k) + head scatter; V transpose
    rope_k<<<dim3(8192), blk, 0, stream>>>(qkv, qh, kh);
    transpose_v<<<dim3(32, 32), blk, 0, stream>>>(qkv, vt);
    // 3) causal flash attention (barrier-free)
    attn_k<<<dim3(32, 32), blk, 0, stream>>>(qh, kh, vt, yws);
    // 4) out = y @ w_proj + b_proj  (fp32)
    gemm_bt<true><<<dim3(32, 8), blk, 0, stream>>>(yws, wpt, b_proj,
                                                   4096, 1024, 1024, out);
    (void)in_sizes; (void)n_in; (void)ws_size; (void)out_size;
}

// Round 11
// 231.734 us; speedup vs baseline: 1.8205x; 1.8205x over previous
//
#include <hip/hip_runtime.h>
#include <hip/hip_bf16.h>
#include <stdint.h>

typedef __hip_bfloat16 bf16;
typedef __attribute__((ext_vector_type(8))) short bf16x8;  // 8 bf16 in 4 VGPRs
typedef __attribute__((ext_vector_type(4))) float f32x4;

__device__ inline float bf2f(bf16 v) { return __bfloat162float(v); }
__device__ inline bf16 f2bf(float f) { return __float2bfloat16(f); }

__device__ inline void glds16(const void* g, void* l) {
    __builtin_amdgcn_global_load_lds(
        (const __attribute__((address_space(1))) uint32_t*)g,
        (__attribute__((address_space(3))) uint32_t*)l, 16, 0, 0);
}

// ---------------- conv_x: fp32 [n] -> bf16 [n], same layout ----------------
__global__ __launch_bounds__(256) void conv_x(const float* __restrict__ in,
                                              bf16* __restrict__ out)
{
    size_t i = ((size_t)blockIdx.x * 256 + threadIdx.x) * 8;
    float4 f0 = *(const float4*)(in + i);
    float4 f1 = *(const float4*)(in + i + 4);
    union { bf16x8 v; bf16 e[8]; } u;
    u.e[0] = f2bf(f0.x); u.e[1] = f2bf(f0.y); u.e[2] = f2bf(f0.z); u.e[3] = f2bf(f0.w);
    u.e[4] = f2bf(f1.x); u.e[5] = f2bf(f1.y); u.e[6] = f2bf(f1.z); u.e[7] = f2bf(f1.w);
    *(bf16x8*)(out + i) = u.v;
}

// ---- conv_wt: fp32 W[K][N] -> bf16 Wt[N][K] (64x64 LDS-tiled transpose) ----
__global__ __launch_bounds__(256) void conv_wt(const float* __restrict__ W,
                                               bf16* __restrict__ Wt, int N, int K)
{
    __shared__ bf16 t[64][72];
    const int n0 = blockIdx.x * 64, k0 = blockIdx.y * 64;
    const int tid = threadIdx.x;
#pragma unroll
    for (int p = 0; p < 4; ++p) {
        int idx = p * 256 + tid;
        int kr = idx >> 4, c4 = idx & 15;
        float4 f = *(const float4*)(W + (size_t)(k0 + kr) * N + n0 + c4 * 4);
        t[kr][c4 * 4 + 0] = f2bf(f.x); t[kr][c4 * 4 + 1] = f2bf(f.y);
        t[kr][c4 * 4 + 2] = f2bf(f.z); t[kr][c4 * 4 + 3] = f2bf(f.w);
    }
    __syncthreads();
#pragma unroll
    for (int p = 0; p < 2; ++p) {
        int idx = p * 256 + tid;
        int nr = idx >> 3, ch = idx & 7;
        union { bf16x8 v; bf16 e[8]; } u;
#pragma unroll
        for (int j = 0; j < 8; ++j) u.e[j] = t[ch * 8 + j][nr];
        *(bf16x8*)(Wt + (size_t)(n0 + nr) * K + k0 + ch * 8) = u.v;
    }
}

// -------- m97-structure GEMM: out[M,N] = A(bf16)[M,K] @ Bt(bf16)[N,K]^T + bias --------
template <bool OUTF32>
__global__ __launch_bounds__(256) void gemm_bt(
    const bf16* __restrict__ A, const bf16* __restrict__ Bt,
    const float* __restrict__ bias, int M, int N, int K, void* __restrict__ outv)
{
    __shared__ __align__(16) bf16 sa[128 * 32];
    __shared__ __align__(16) bf16 sb[128 * 32];

    const int tid  = threadIdx.x;
    const int wave = tid >> 6, lane = tid & 63;
    const int quad = lane >> 4, l16 = lane & 15;
    const int wm = wave >> 1, wn = wave & 1;
    const int row0 = blockIdx.x * 128, n0 = blockIdx.y * 128;

    f32x4 acc[4][4] = {};

    const int sm = wave * 16 + (lane >> 2);
    const int sk = (lane & 3) * 8;
    const bf16* ga = A  + (size_t)(row0 + sm) * K + sk;
    const bf16* gb = Bt + (size_t)(n0  + sm) * K + sk;
    bf16* la = sa + wave * 512;
    bf16* lb = sb + wave * 512;

    for (int k0 = 0; k0 < K; k0 += 32) {
        __syncthreads();
        glds16(ga + k0, la);
        glds16(ga + k0 + (size_t)64 * K, la + 2048);
        glds16(gb + k0, lb);
        glds16(gb + k0 + (size_t)64 * K, lb + 2048);
        __syncthreads();

        bf16x8 af[4], bfr[4];
#pragma unroll
        for (int mi = 0; mi < 4; ++mi)
            af[mi] = *(const bf16x8*)&sa[(wm * 64 + mi * 16 + l16) * 32 + quad * 8];
#pragma unroll
        for (int ni = 0; ni < 4; ++ni)
            bfr[ni] = *(const bf16x8*)&sb[(wn * 64 + ni * 16 + l16) * 32 + quad * 8];
#pragma unroll
        for (int mi = 0; mi < 4; ++mi)
#pragma unroll
            for (int ni = 0; ni < 4; ++ni)
                acc[mi][ni] = __builtin_amdgcn_mfma_f32_16x16x32_bf16(
                    af[mi], bfr[ni], acc[mi][ni], 0, 0, 0);
    }

#pragma unroll
    for (int ni = 0; ni < 4; ++ni) {
        int col = n0 + wn * 64 + ni * 16 + l16;
        float bvv = bias[col];
#pragma unroll
        for (int mi = 0; mi < 4; ++mi) {
#pragma unroll
            for (int r = 0; r < 4; ++r) {
                int row = row0 + wm * 64 + mi * 16 + quad * 4 + r;
                float v = acc[mi][ni][r] + bvv;
                if (OUTF32) ((float*)outv)[(size_t)row * N + col] = v;
                else        ((bf16*)outv)[(size_t)row * N + col] = f2bf(v);
            }
        }
    }
}

// ---- rope_k: qkv[4096][3072] bf16 -> q,k [bh][t][64] bf16 (q scaled 0.125) ----
__global__ __launch_bounds__(256) void rope_k(
    const bf16* __restrict__ qkv, bf16* __restrict__ q, bf16* __restrict__ k)
{
    int gid = blockIdx.x * 256 + threadIdx.x;
    int p  = gid & 31, d0 = p * 2;
    int t  = (gid >> 5) & 2047;
    int h  = (gid >> 16) & 15;
    int b  = gid >> 20;

    size_t src = ((size_t)(b * 2048 + t)) * 3072 + h * 64 + d0;
    size_t dst = (((size_t)(b * 16 + h)) * 2048 + t) * 64 + d0;

    float invf = expf(-(float)d0 * (9.210340371976184f / 64.0f));
    float sn, cs;
    sincosf((float)t * invf, &sn, &cs);

    float q0 = bf2f(qkv[src]),        q1 = bf2f(qkv[src + 1]);
    float k0 = bf2f(qkv[src + 1024]), k1 = bf2f(qkv[src + 1025]);
    q[dst]     = f2bf((q0 * cs - q1 * sn) * 0.125f);
    q[dst + 1] = f2bf((q1 * cs + q0 * sn) * 0.125f);
    k[dst]     = f2bf(k0 * cs - k1 * sn);
    k[dst + 1] = f2bf(k1 * cs + k0 * sn);
}

// ---- transpose_v: qkv v-part -> vt [bh][64 d][2048 t] ----
__global__ __launch_bounds__(256) void transpose_v(
    const bf16* __restrict__ qkv, bf16* __restrict__ vt)
{
    __shared__ bf16 t[64][72];
    const int t0 = blockIdx.x * 64;
    const int bh = blockIdx.y, b = bh >> 4, h = bh & 15;
    const int tid = threadIdx.x;
#pragma unroll
    for (int p = 0; p < 2; ++p) {
        int idx = p * 256 + tid;
        int tr = idx >> 3, ch = idx & 7;
        bf16x8 v = *(const bf16x8*)(qkv + ((size_t)(b * 2048 + t0 + tr)) * 3072
                                    + 2048 + h * 64 + ch * 8);
#pragma unroll
        for (int j = 0; j < 8; ++j) t[tr][ch * 8 + j] = ((const bf16*)&v)[j];
    }
    __syncthreads();
#pragma unroll
    for (int p = 0; p < 2; ++p) {
        int idx = p * 256 + tid;
        int dr = idx >> 3, ch = idx & 7;
        union { bf16x8 v; bf16 e[8]; } u;
#pragma unroll
        for (int j = 0; j < 8; ++j) u.e[j] = t[ch * 8 + j][dr];
        *(bf16x8*)(vt + ((size_t)bh * 64 + dr) * 2048 + t0 + ch * 8) = u.v;
    }
}

// ---- Flash attention, causal. LDS-staged K/V (glds16, XOR-swizzled),
// work-balanced: block = (bh, pair), handles q-tiles pair and 31-pair. ----
__global__ __launch_bounds__(256) void attn_k(
    const bf16* __restrict__ qg, const bf16* __restrict__ kg,
    const bf16* __restrict__ vtg, bf16* __restrict__ y)
{
    __shared__ __align__(16) bf16 sK[128 * 64];     // [key][64], chunk p = (c^key)&7
    __shared__ __align__(16) bf16 sV[64 * 128];     // [d][128],  chunk p = (c^d)&15
    __shared__ __align__(16) bf16 pL[4][16][136];   // per-wave P, XOR-chunk swizzle

    const int tid  = threadIdx.x;
    const int wave = tid >> 6, lane = tid & 63;
    const int quad = lane >> 4, l16 = lane & 15;
    const int bh   = blockIdx.x;
    const int pair = blockIdx.y;
    const bf16* Q  = qg  + (size_t)bh * 2048 * 64;
    const bf16* K  = kg  + (size_t)bh * 2048 * 64;
    const bf16* Vt = vtg + (size_t)bh * 64 * 2048;
    const int b = bh >> 4, h = bh & 15;

    for (int half = 0; half < 2; ++half) {
        const int qt = half ? (31 - pair) : pair;
        const int q0 = qt * 64 + wave * 16;

        bf16x8 aq[2];
        aq[0] = *(const bf16x8*)(Q + (size_t)(q0 + l16) * 64 + quad * 8);
        aq[1] = *(const bf16x8*)(Q + (size_t)(q0 + l16) * 64 + 32 + quad * 8);

        f32x4 o[4] = {};
        float m_r[4] = {-1e30f, -1e30f, -1e30f, -1e30f};
        float l_r[4] = {0.f, 0.f, 0.f, 0.f};

        for (int kt = 0; kt <= q0 + 15; kt += 128) {   // uniform iters across waves
            __syncthreads();
            // ---- stage K tile: keys kt..kt+127 x 64d ----
#pragma unroll
            for (int c = 0; c < 4; ++c) {
                int key = wave * 32 + c * 8 + (lane >> 3);
                int p = lane & 7;
                glds16(K + (size_t)(kt + key) * 64 + ((p ^ key) & 7) * 8,
                       &sK[(wave * 32 + c * 8) * 64]);
            }
            // ---- stage V^T tile: 64d x t kt..kt+127 ----
#pragma unroll
            for (int c = 0; c < 4; ++c) {
                int d = wave * 16 + c * 4 + (lane >> 4);
                int p = lane & 15;
                glds16(Vt + (size_t)d * 2048 + kt + ((p ^ d) & 15) * 8,
                       &sV[(wave * 16 + c * 4) * 128]);
            }
            __syncthreads();

            const int nlast = min(7, (q0 - kt) >> 4);
            f32x4 sc[8];
            // ---- S = Q K^T ----
#pragma unroll
            for (int nt = 0; nt < 8; ++nt) {
                if (nt > nlast) continue;
                int key = nt * 16 + l16;
                f32x4 s0 = {};
                bf16x8 bk0 = *(const bf16x8*)&sK[key * 64 + ((quad ^ key) & 7) * 8];
                s0 = __builtin_amdgcn_mfma_f32_16x16x32_bf16(aq[0], bk0, s0, 0, 0, 0);
                bf16x8 bk1 = *(const bf16x8*)&sK[key * 64 + (((4 + quad) ^ key) & 7) * 8];
                sc[nt] = __builtin_amdgcn_mfma_f32_16x16x32_bf16(aq[1], bk1, s0, 0, 0, 0);
            }
            // ---- causal mask: diagonal subtile only ----
            {
                const int diag = (q0 - kt) >> 4;
                if (diag <= 7) {
                    int key = kt + diag * 16 + l16;
#pragma unroll
                    for (int r = 0; r < 4; ++r) {
                        int row = q0 + quad * 4 + r;
                        if (key > row) sc[diag][r] = -1e30f;
                    }
                }
            }
            // ---- online softmax ----
            float rowmax[4] = {-1e30f, -1e30f, -1e30f, -1e30f};
#pragma unroll
            for (int nt = 0; nt < 8; ++nt) {
                if (nt > nlast) continue;
#pragma unroll
                for (int r = 0; r < 4; ++r) rowmax[r] = fmaxf(rowmax[r], sc[nt][r]);
            }
#pragma unroll
            for (int off = 1; off < 16; off <<= 1)
#pragma unroll
                for (int r = 0; r < 4; ++r)
                    rowmax[r] = fmaxf(rowmax[r], __shfl_xor(rowmax[r], off));

            float alpha[4];
#pragma unroll
            for (int r = 0; r < 4; ++r) {
                float mn = fmaxf(m_r[r], rowmax[r]);
                alpha[r] = __expf(m_r[r] - mn);
                m_r[r] = mn;
            }
            float rs[4] = {0.f, 0.f, 0.f, 0.f};
#pragma unroll
            for (int nt = 0; nt < 8; ++nt) {
                if (nt > nlast) continue;
#pragma unroll
                for (int r = 0; r < 4; ++r) {
                    float p = __expf(sc[nt][r] - m_r[r]);
                    sc[nt][r] = p;
                    rs[r] += p;
                }
            }
#pragma unroll
            for (int off = 1; off < 16; off <<= 1)
#pragma unroll
                for (int r = 0; r < 4; ++r) rs[r] += __shfl_xor(rs[r], off);
#pragma unroll
            for (int r = 0; r < 4; ++r) l_r[r] = l_r[r] * alpha[r] + rs[r];
#pragma unroll
            for (int nt = 0; nt < 4; ++nt)
#pragma unroll
                for (int r = 0; r < 4; ++r) o[nt][r] *= alpha[r];

            // ---- P -> per-wave LDS (swizzled), wave-private ----
#pragma unroll
            for (int nt = 0; nt < 8; ++nt) {
                if (nt > nlast) continue;
                int blk = (2 * nt + (l16 >> 3)) ^ quad;
#pragma unroll
                for (int r = 0; r < 4; ++r)
                    pL[wave][quad * 4 + r][blk * 8 + (l16 & 7)] = f2bf(sc[nt][r]);
            }
            if (nlast < 7 && !(nlast & 1)) {
                int blk = (2 * (nlast + 1) + (l16 >> 3)) ^ quad;
#pragma unroll
                for (int r = 0; r < 4; ++r)
                    pL[wave][quad * 4 + r][blk * 8 + (l16 & 7)] = f2bf(0.f);
            }
            // ---- O += P V ----
#pragma unroll
            for (int c = 0; c < 4; ++c) {
                if (c > (nlast >> 1)) continue;
                bf16x8 pa = *(const bf16x8*)&pL[wave][l16][(((4 * c + quad) ^ (l16 >> 2)) * 8)];
#pragma unroll
                for (int dnt = 0; dnt < 4; ++dnt) {
                    int d = dnt * 16 + l16;
                    int cc = c * 4 + quad;
                    bf16x8 vb = *(const bf16x8*)&sV[d * 128 + ((cc ^ d) & 15) * 8];
                    o[dnt] = __builtin_amdgcn_mfma_f32_16x16x32_bf16(pa, vb, o[dnt], 0, 0, 0);
                }
            }
        }

        // epilogue for this half
#pragma unroll
        for (int r = 0; r < 4; ++r) {
            float inv = 1.0f / l_r[r];
            int qq = q0 + quad * 4 + r;
#pragma unroll
            for (int nt = 0; nt < 4; ++nt) {
                int d = nt * 16 + l16;
                y[((size_t)(b * 2048 + qq)) * 1024 + h * 64 + d] = f2bf(o[nt][r] * inv);
            }
        }
    }
}

extern "C" void kernel_launch(void* const* d_in, const int* in_sizes, int n_in,
                              void* d_out, int out_size, void* d_ws, size_t ws_size,
                              hipStream_t stream) {
    const float* x      = (const float*)d_in[0];
    const float* w_attn = (const float*)d_in[1];
    const float* b_attn = (const float*)d_in[2];
    const float* w_proj = (const float*)d_in[3];
    const float* b_proj = (const float*)d_in[4];
    float* out = (float*)d_out;

    bf16* xbf = (bf16*)d_ws;                         // [4096][1024]
    bf16* wat = xbf + (size_t)4194304;               // [3072][1024] (B^T)
    bf16* wpt = wat + (size_t)3145728;               // [1024][1024] (B^T)
    bf16* qkv = wpt + (size_t)1048576;               // [4096][3072]
    bf16* qh  = qkv + (size_t)12582912;              // [bh][2048][64]
    bf16* kh  = qh  + (size_t)4194304;
    bf16* vt  = kh  + (size_t)4194304;               // [bh][64][2048]
    bf16* yws = vt  + (size_t)4194304;               // [4096][1024]

    dim3 blk(256);
    conv_x<<<dim3(2048), blk, 0, stream>>>(x, xbf);
    conv_wt<<<dim3(48, 16), blk, 0, stream>>>(w_attn, wat, 3072, 1024);
    conv_wt<<<dim3(16, 16), blk, 0, stream>>>(w_proj, wpt, 1024, 1024);
    gemm_bt<false><<<dim3(32, 24), blk, 0, stream>>>(xbf, wat, b_attn,
                                                     4096, 3072, 1024, qkv);
    rope_k<<<dim3(8192), blk, 0, stream>>>(qkv, qh, kh);
    transpose_v<<<dim3(32, 32), blk, 0, stream>>>(qkv, vt);
    // balanced flash attention: grid (bh, pair)
    attn_k<<<dim3(32, 16), blk, 0, stream>>>(qh, kh, vt, yws);
    gemm_bt<true><<<dim3(32, 8), blk, 0, stream>>>(yws, wpt, b_proj,
                                                   4096, 1024, 1024, out);
    (void)in_sizes; (void)n_in; (void)ws_size; (void)out_size;
}